// Round 8
// baseline (795.258 us; speedup 1.0000x reference)
//
#include <hip/hip_runtime.h>
#include <hip/hip_bf16.h>
#include <cstdint>

// ---------- types ----------
typedef __bf16 bf16x8 __attribute__((ext_vector_type(8)));
typedef float f32x4 __attribute__((ext_vector_type(4)));
typedef unsigned short u16;
typedef unsigned short u16x8 __attribute__((ext_vector_type(8)));
typedef unsigned short u16x4 __attribute__((ext_vector_type(4)));

#define EMBED 1024
#define HIDDEN 512
#define SEQ 4096
#define NBATCH 4
#define MTOT (NBATCH * SEQ)  // 16384
#define KVSPLIT 2
#define QT 128               // q-rows per flash block (8 waves x 16 rows)

__device__ __forceinline__ u16 f32_to_bf16(float f) {
  union { float f; uint32_t u; } v; v.f = f;
  uint32_t r = v.u + 0x7fffu + ((v.u >> 16) & 1u);
  return (u16)(r >> 16);
}

// async global->LDS, 16B per lane; lds dst MUST be wave-uniform; HW adds lane*16B
__device__ __forceinline__ void load_lds16(const u16* g, u16* l) {
  __builtin_amdgcn_global_load_lds(
      (const __attribute__((address_space(1))) void*)g,
      (__attribute__((address_space(3))) void*)l, 16, 0, 0);
}

// ---------- elementwise f32 -> bf16 ----------
__global__ __launch_bounds__(256) void cvt_bf16_kernel(const float* __restrict__ src,
                                                       u16* __restrict__ dst) {
  int i = blockIdx.x * 256 + threadIdx.x;
  float4 v = ((const float4*)src)[i];
  u16x4 o;
  o[0] = f32_to_bf16(v.x); o[1] = f32_to_bf16(v.y);
  o[2] = f32_to_bf16(v.z); o[3] = f32_to_bf16(v.w);
  ((u16x4*)dst)[i] = o;
}

// ---------- weight transpose+convert: src[K][N] f32 -> dst[N][K] bf16 ----------
__global__ __launch_bounds__(256) void transpose_w_kernel(const float* __restrict__ src,
                                                          u16* __restrict__ dst,
                                                          int log2N, int K) {
  int idx = blockIdx.x * 256 + threadIdx.x;
  int N = 1 << log2N;
  int k = idx >> log2N;
  int n = idx & (N - 1);
  dst[(size_t)n * K + k] = f32_to_bf16(src[idx]);
}

// ---------- GEMM: C[M,N] = A[M,K] * Bt[N,K]^T  (bf16 in, fp32 acc) ----------
// m97 structure: width-16 global_load_lds staging into UNPADDED [128][32] tiles.
// LDS dst is WAVE-UNIFORM (&As[16*wave][0]); HW writes base + lane*16B, so lane L
// covers (row = 16*wave + L/4, lds col-block = L&3). Global source col-block is
// pre-swizzled by (row>>1)&3 (rule #21); ds_read applies the same XOR.
// MODE 0: bf16 out * scale
// MODE 1: bf16 out, + bias[col] + resid[row*ldc+col]
// MODE 2: fp32 out
// MODE 3: bf16 out TRANSPOSED per batch: Vt[(batch*512+col)*4096 + (row&4095)]
template <int MODE>
__global__ __launch_bounds__(256, 3) void gemm_bt_kernel(
    const u16* __restrict__ A, const u16* __restrict__ Bt, void* __restrict__ Cout,
    const float* __restrict__ bias, const float* __restrict__ resid,
    int ldc, int K, float scale) {
  __shared__ u16 As[128][32];
  __shared__ u16 Bs[128][32];
  const int tid = threadIdx.x;
  const int lane = tid & 63;
  const int wave = tid >> 6;
  const int quad = lane >> 4;
  const int l15 = lane & 15;
  const int m0 = blockIdx.x * 128;
  const int n0 = blockIdx.y * 128;
  const int wm = (wave & 1) * 64;
  const int wn = (wave >> 1) * 64;

  // staging: lane L of wave w covers row 16w + L/4 (chunk0) / +64 (chunk1),
  // source col-block swizzled by ((row within 16)>>1)&3 = (L>>3)&3.
  const int rw = wave * 16 + (lane >> 2);
  const int cb = ((lane & 3) ^ ((lane >> 3) & 3)) * 8;
  const u16* pa0 = &A[(size_t)(m0 + rw) * K + cb];
  const u16* pb0 = &Bt[(size_t)(n0 + rw) * K + cb];
  u16* lA = &As[wave * 16][0];   // wave-uniform LDS base
  u16* lB = &Bs[wave * 16][0];

  f32x4 acc[4][4];
#pragma unroll
  for (int i = 0; i < 4; ++i)
#pragma unroll
    for (int j = 0; j < 4; ++j) {
      acc[i][j][0] = 0.f; acc[i][j][1] = 0.f; acc[i][j][2] = 0.f; acc[i][j][3] = 0.f;
    }

  for (int k0 = 0; k0 < K; k0 += 32) {
    __syncthreads();
    load_lds16(pa0 + k0, lA);
    load_lds16(pa0 + k0 + (size_t)64 * K, lA + 64 * 32);   // rows 64..127
    load_lds16(pb0 + k0, lB);
    load_lds16(pb0 + k0 + (size_t)64 * K, lB + 64 * 32);
    __syncthreads();                                       // drains vmcnt(0): tiles ready
    bf16x8 af[4], bfr[4];
#pragma unroll
    for (int i = 0; i < 4; ++i)
      af[i] = *(const bf16x8*)&As[wm + i * 16 + l15][(quad ^ ((l15 >> 1) & 3)) * 8];
#pragma unroll
    for (int j = 0; j < 4; ++j)
      bfr[j] = *(const bf16x8*)&Bs[wn + j * 16 + l15][(quad ^ ((l15 >> 1) & 3)) * 8];
#pragma unroll
    for (int i = 0; i < 4; ++i)
#pragma unroll
      for (int j = 0; j < 4; ++j)
        acc[i][j] = __builtin_amdgcn_mfma_f32_16x16x32_bf16(af[i], bfr[j], acc[i][j], 0, 0, 0);
  }

  // epilogue: C/D layout col=lane&15, row=quad*4+reg  [guide m89/m91]
#pragma unroll
  for (int i = 0; i < 4; ++i) {
    const int row = m0 + wm + i * 16 + quad * 4;
#pragma unroll
    for (int j = 0; j < 4; ++j) {
      const int col = n0 + wn + j * 16 + l15;
#pragma unroll
      for (int r = 0; r < 4; ++r) {
        float v = acc[i][j][r];
        const int rr = row + r;
        if (MODE == 0) {
          ((u16*)Cout)[(size_t)rr * ldc + col] = f32_to_bf16(v * scale);
        } else if (MODE == 1) {
          const size_t off = (size_t)rr * ldc + col;
          v += bias[col] + resid[off];
          ((u16*)Cout)[off] = f32_to_bf16(v);
        } else if (MODE == 2) {
          ((float*)Cout)[(size_t)rr * ldc + col] = v;
        } else {
          // transposed V store
          ((u16*)Cout)[((size_t)((rr >> 12) * 512 + col) << 12) + (rr & 4095)] = f32_to_bf16(v);
        }
      }
    }
  }
}

// ---------- flash attention (2-way KV split, Q-tile 128, d-slice PV) ----------
// QKV: [16384, 1024] bf16 rows (Q|K), Q pre-scaled by log2(e)/sqrt(512).
// VtG: [4][512][4096] bf16 (V transposed per batch).
// grid (SEQ/QT=32, NBATCH, KVSPLIT); block 512 = 8 waves.
// Phase A (per wave, its own q-group g=wave): QK^T 16q x 32kv, exp2, publish P.
// Phase B (after barrier): wave w owns d-slice nt in [4w,4w+4) for ALL 8 groups —
// V frags read ONCE per iter (4 b128, reused across groups); P frags 8 b128.
// R7 lesson: __launch_bounds__(512, 2) imposes a 256-reg/wave cap (unified
// VGPR+AGPR file / 2 waves per EU); this kernel needs ~256+ so the allocator
// spilled ~16 f32/thread/iter (595 MB WRITE). LDS (142 KB) already limits us to
// 1 block/CU = 2 waves/SIMD, so min_waves=2 bought nothing. Use (512, 1):
// cap 512, no spill, same occupancy.
// NO max-subtraction (scores bounded; exp2 domain); lane-local l, epilogue reduce.
// 2-phase dbuf pipeline: STAGE(next) at iter top; vmcnt(0)+barrier at iter end.
__global__ __launch_bounds__(512, 1) void flash_kernel(const u16* __restrict__ QKV,
                                                       const u16* __restrict__ VtG,
                                                       float* __restrict__ Opart,
                                                       float* __restrict__ ml) {
  __shared__ u16 Ks[2][32][520];   // K tile [kv][d], pad 512+8; epilogue scratch alias
  __shared__ u16 Vs[2][512][32];   // V^T tile [d][kv]; col-block XOR-swizzled by (row>>1)&3
  __shared__ u16 Ps[8][16][40];    // P tiles [group][q][kv] (80B rows: 16B-aligned, 2-way max)
  const int tid = threadIdx.x;
  const int lane = tid & 63;
  const int wave = tid >> 6;       // 0..7 = q-group (phase A) and d-slice owner (phase B)
  const int quad = lane >> 4;
  const int l15 = lane & 15;
  // --- XCD-aware remap: raw = bx + 32*by + 128*bz in [0,256); id%8 picks XCD.
  const int raw = blockIdx.x + 32 * blockIdx.y + 128 * blockIdx.z;
  const int xh = raw >> 3;
  const int g8 = raw & 7;
  const int yh = g8 >> 1;
  const int zh = g8 & 1;
  const int base = yh * SEQ;
  const int b512 = yh * 512;
  const int q0 = xh * QT;
  const int kvb = zh * (SEQ / KVSPLIT);

  // Q fragments resident in registers: A-layout m=lane&15, k=quad*8+j  [guide m120]
  bf16x8 qf[16];
  {
    const u16* qp = QKV + (size_t)(base + q0 + wave * 16 + l15) * 1024 + quad * 8;
#pragma unroll
    for (int ks = 0; ks < 16; ++ks) qf[ks] = *(const bf16x8*)(qp + ks * 32);
  }

  // O[g][j]: q-group g, local d-tile j (global nt = wave*4+j). ALL accesses
  // statically indexed (rule #20).
  f32x4 O[8][4];
#pragma unroll
  for (int g = 0; g < 8; ++g)
#pragma unroll
    for (int j = 0; j < 4; ++j) { O[g][j][0] = 0.f; O[g][j][1] = 0.f; O[g][j][2] = 0.f; O[g][j][3] = 0.f; }
  float l_run[4] = {0.f, 0.f, 0.f, 0.f};  // lane-local partial row-sums (group=wave)

  // stage one 32-kv tile (K 32KB + V^T 32KB) into buffer b: 8 loads/wave
  auto STAGE = [&](int b, int kv0) {
    const u16* kp = QKV + (size_t)(base + kv0 + wave * 4) * 1024 + 512 + lane * 8;
    const u16* vp = VtG + (size_t)(b512 + wave * 64 + (lane >> 2)) * 4096 + kv0 +
                    (((lane & 3) ^ ((lane >> 3) & 3)) * 8);
#pragma unroll
    for (int p = 0; p < 4; ++p) {
      load_lds16(kp + (size_t)p * 1024, &Ks[b][wave * 4 + p][0]);
      load_lds16(vp + (size_t)(p * 16) * 4096, &Vs[b][wave * 64 + p * 16][0]);
    }
  };

  const int nIter = (SEQ / KVSPLIT) / 32;  // 64
  STAGE(0, kvb);
  asm volatile("s_waitcnt vmcnt(0)" ::: "memory");
  __builtin_amdgcn_s_barrier();
  int cur = 0;

  for (int t = 0; t < nIter; ++t) {
    if (t + 1 < nIter) STAGE(cur ^ 1, kvb + (t + 1) * 32);

    // Phase A: S tile for own q-group (16 q x 32 kv)
    f32x4 s0, s1;
    s0[0] = 0.f; s0[1] = 0.f; s0[2] = 0.f; s0[3] = 0.f;
    s1[0] = 0.f; s1[1] = 0.f; s1[2] = 0.f; s1[3] = 0.f;
    __builtin_amdgcn_s_setprio(1);
#pragma unroll
    for (int ks = 0; ks < 16; ++ks) {
      bf16x8 b0 = *(const bf16x8*)&Ks[cur][l15][ks * 32 + quad * 8];
      bf16x8 b1 = *(const bf16x8*)&Ks[cur][16 + l15][ks * 32 + quad * 8];
      s0 = __builtin_amdgcn_mfma_f32_16x16x32_bf16(qf[ks], b0, s0, 0, 0, 0);
      s1 = __builtin_amdgcn_mfma_f32_16x16x32_bf16(qf[ks], b1, s1, 0, 0, 0);
    }
    __builtin_amdgcn_s_setprio(0);

    // preload this wave's 4 V frags (valid all iter; overlaps softmax VALU)
    bf16x8 vf[4];
#pragma unroll
    for (int j = 0; j < 4; ++j)
      vf[j] = *(const bf16x8*)&Vs[cur][(wave * 4 + j) * 16 + l15][(quad ^ ((l15 >> 1) & 3)) * 8];

    // softmax numerator: p = exp2(s); lane-local row-sum
    float p0[4], p1[4];
#pragma unroll
    for (int r = 0; r < 4; ++r) {
      p0[r] = __builtin_amdgcn_exp2f(s0[r]);
      p1[r] = __builtin_amdgcn_exp2f(s1[r]);
      l_run[r] += p0[r] + p1[r];
    }

    // publish P (C-layout scatter): group=wave rows, cols l15 / 16+l15
#pragma unroll
    for (int r = 0; r < 4; ++r) {
      Ps[wave][quad * 4 + r][l15] = f32_to_bf16(p0[r]);
      Ps[wave][quad * 4 + r][16 + l15] = f32_to_bf16(p1[r]);
    }
    asm volatile("s_waitcnt lgkmcnt(0)" ::: "memory");
    __builtin_amdgcn_s_barrier();    // #1: all P visible

    // Phase B: d-slice PV — 8 P reads + 4 resident V frags -> 32 MFMA
    __builtin_amdgcn_s_setprio(1);
#pragma unroll
    for (int g = 0; g < 8; ++g) {
      bf16x8 pf = *(const bf16x8*)&Ps[g][l15][quad * 8];
#pragma unroll
      for (int j = 0; j < 4; ++j)
        O[g][j] = __builtin_amdgcn_mfma_f32_16x16x32_bf16(pf, vf[j], O[g][j], 0, 0, 0);
    }
    __builtin_amdgcn_s_setprio(0);

    // #2: stage drained (next tiles ready) + all Ps reads done (safe to rewrite)
    asm volatile("s_waitcnt vmcnt(0) lgkmcnt(0)" ::: "memory");
    __builtin_amdgcn_s_barrier();
    cur ^= 1;
  }

  // epilogue: reduce l within quad (16 lanes hold the kv-slices of rows quad*4+r)
#pragma unroll
  for (int m = 1; m <= 8; m <<= 1)
#pragma unroll
    for (int r = 0; r < 4; ++r) l_run[r] += __shfl_xor(l_run[r], m);

  // l for own q-group (m=0 placeholder kept for combine kernel)
  if (l15 == 0) {
    const int qrow = base + q0 + wave * 16 + quad * 4;
#pragma unroll
    for (int r = 0; r < 4; ++r) {
      ml[((size_t)zh * MTOT + qrow + r) * 2 + 0] = 0.0f;
      ml[((size_t)zh * MTOT + qrow + r) * 2 + 1] = l_run[r];
    }
  }

  // epilogue O write: per group, gather d-slices in LDS then write coalesced rows.
  // sO [16][516] f32; FULLY UNROLLED group loop (rule #20: keep O in VGPRs).
  float* sO = (float*)&Ks[0][0][0];  // 33,024 B scratch, Ks dead after loop
  const int erow = tid >> 5;         // 0..15
  const int ecol = (tid & 31) * 16;  // 0..496
#pragma unroll
  for (int g = 0; g < 8; ++g) {
    // deposit: wave's d-slice of group g; row = quad*4+r, col = wave*64+j*16+l15
#pragma unroll
    for (int j = 0; j < 4; ++j)
#pragma unroll
      for (int r = 0; r < 4; ++r)
        sO[(quad * 4 + r) * 516 + wave * 64 + j * 16 + l15] = O[g][j][r];
    __syncthreads();
    // write 16 rows x 2KB contiguous: thread covers 64B of its row
    float* dst = Opart + ((size_t)zh * MTOT + base + q0 + g * 16 + erow) * HIDDEN + ecol;
    const float* srcp = sO + erow * 516 + ecol;
#pragma unroll
    for (int q = 0; q < 4; ++q)
      ((float4*)dst)[q] = ((const float4*)srcp)[q];
    __syncthreads();  // before next group overwrites sO
  }
}

// ---------- combine KV-split partials -> bf16 ctx ----------
__global__ __launch_bounds__(128) void combine_kernel(const float* __restrict__ Op,
                                                      const float* __restrict__ ml,
                                                      u16* __restrict__ ctx) {
  const int row = blockIdx.x;
  const int tid = threadIdx.x;  // 128 threads x float4 = 512 cols
  const float m1 = ml[(size_t)row * 2], l1 = ml[(size_t)row * 2 + 1];
  const float m2 = ml[((size_t)MTOT + row) * 2], l2 = ml[((size_t)MTOT + row) * 2 + 1];
  const float M = fmaxf(m1, m2);
  const float w1 = __expf(m1 - M), w2 = __expf(m2 - M);
  const float den = 1.0f / (w1 * l1 + w2 * l2);
  float4 a = ((const float4*)(Op + (size_t)row * HIDDEN))[tid];
  float4 b = ((const float4*)(Op + ((size_t)MTOT + row) * HIDDEN))[tid];
  u16x4 o;
  o[0] = f32_to_bf16((a.x * w1 + b.x * w2) * den);
  o[1] = f32_to_bf16((a.y * w1 + b.y * w2) * den);
  o[2] = f32_to_bf16((a.z * w1 + b.z * w2) * den);
  o[3] = f32_to_bf16((a.w * w1 + b.w * w2) * den);
  ((u16x4*)(ctx + (size_t)row * HIDDEN))[tid] = o;
}

// ---------- layernorm (in-place on d_out fp32, 1024 cols/row) ----------
__global__ __launch_bounds__(256) void ln_kernel(float* __restrict__ io,
                                                 const float* __restrict__ g,
                                                 const float* __restrict__ b) {
  const int row = blockIdx.x;
  const int tid = threadIdx.x;
  float* x = io + (size_t)row * EMBED;
  float4 v = *(const float4*)(x + tid * 4);
  float s1 = v.x + v.y + v.z + v.w;
  float s2 = v.x * v.x + v.y * v.y + v.z * v.z + v.w * v.w;
#pragma unroll
  for (int m = 1; m <= 32; m <<= 1) {
    s1 += __shfl_xor(s1, m);
    s2 += __shfl_xor(s2, m);
  }
  __shared__ float rs1[4], rs2[4];
  const int wave = tid >> 6;
  if ((tid & 63) == 0) { rs1[wave] = s1; rs2[wave] = s2; }
  __syncthreads();
  s1 = rs1[0] + rs1[1] + rs1[2] + rs1[3];
  s2 = rs2[0] + rs2[1] + rs2[2] + rs2[3];
  const float mu = s1 * (1.f / EMBED);
  const float var = s2 * (1.f / EMBED) - mu * mu;
  const float rinv = rsqrtf(var + 1e-5f);
  float4 gg = *(const float4*)(g + tid * 4);
  float4 bb = *(const float4*)(b + tid * 4);
  float4 o;
  o.x = (v.x - mu) * rinv * gg.x + bb.x;
  o.y = (v.y - mu) * rinv * gg.y + bb.y;
  o.z = (v.z - mu) * rinv * gg.z + bb.z;
  o.w = (v.w - mu) * rinv * gg.w + bb.w;
  *(float4*)(x + tid * 4) = o;
}

// ---------- launch ----------
extern "C" void kernel_launch(void* const* d_in, const int* in_sizes, int n_in,
                              void* d_out, int out_size, void* d_ws, size_t ws_size,
                              hipStream_t stream) {
  const float* q_feat = (const float*)d_in[0];
  const float* kv_feat = (const float*)d_in[1];
  const float* Wq = (const float*)d_in[2];
  const float* Wk = (const float*)d_in[3];
  const float* Wv = (const float*)d_in[4];
  const float* Wo = (const float*)d_in[5];
  const float* bo = (const float*)d_in[6];
  const float* Wfc = (const float*)d_in[7];
  const float* ln_g = (const float*)d_in[8];
  const float* ln_b = (const float*)d_in[9];
  float* out = (float*)d_out;

  // ws carve (total 140,509,184 B)
  char* ws = (char*)d_ws;
  u16* Aq    = (u16*)(ws + 0);           // 33,554,432  (later aliased as Opart/out1)
  u16* Akv   = (u16*)(ws + 33554432);    // 33,554,432  (later aliased as Opart upper half)
  u16* Wcat  = (u16*)(ws + 67108864);    //  3,145,728  [1536,1024] bf16 (Wq^T|Wk^T|Wv^T); later ml
  u16* Wo_t  = (u16*)(ws + 70254592);    //  1,048,576  [1024,512]
  u16* Wfc_t = (u16*)(ws + 71303168);    //  2,097,152  [1024,1024]
  u16* QKV   = (u16*)(ws + 73400320);    // 33,554,432  [16384,1024] (Q|K)
  u16* Vt    = (u16*)(ws + 106954752);   // 16,777,216  [4][512][4096]
  u16* ctx   = (u16*)(ws + 123731968);   // 16,777,216  [16384,512]
  u16* out1  = Aq;                       // alias: Aq dead after Q-projection
  // flash partials alias dead regions: Aq+Akv (dead after projections) hold
  // Opart [2][16384][512] f32 = 67,108,864 B; first 256 KB of Wcat (dead after
  // projections) holds ml [2][16384][2] f32 = 262,144 B.
  float* Opart = (float*)(ws + 0);
  float* mlp   = (float*)(ws + 67108864);

  // Q pre-scale: log2(e)/sqrt(512) so scores arrive in log2 domain (p = exp2(s))
  const float qscale = 0.063762994f;

  // 1. activations -> bf16
  cvt_bf16_kernel<<<MTOT * EMBED / 1024, 256, 0, stream>>>(q_feat, Aq);
  cvt_bf16_kernel<<<MTOT * EMBED / 1024, 256, 0, stream>>>(kv_feat, Akv);
  // 2. weights -> transposed bf16
  transpose_w_kernel<<<(EMBED * HIDDEN) / 256, 256, 0, stream>>>(Wq, Wcat, 9, EMBED);
  transpose_w_kernel<<<(EMBED * HIDDEN) / 256, 256, 0, stream>>>(Wk, Wcat + 512 * 1024, 9, EMBED);
  transpose_w_kernel<<<(EMBED * HIDDEN) / 256, 256, 0, stream>>>(Wv, Wcat + 1024 * 1024, 9, EMBED);
  transpose_w_kernel<<<(HIDDEN * EMBED) / 256, 256, 0, stream>>>(Wo, Wo_t, 10, HIDDEN);
  transpose_w_kernel<<<(EMBED * EMBED) / 256, 256, 0, stream>>>(Wfc, Wfc_t, 10, EMBED);
  // 3a. Q projection from q_feat (pre-scaled): QKV cols [0,512)
  gemm_bt_kernel<0><<<dim3(MTOT / 128, 4), 256, 0, stream>>>(
      Aq, Wcat, QKV, nullptr, nullptr, 1024, EMBED, qscale);
  // 3b. K projection from kv_feat: QKV cols [512,1024)
  gemm_bt_kernel<0><<<dim3(MTOT / 128, 4), 256, 0, stream>>>(
      Akv, Wcat + 512 * 1024, QKV + 512, nullptr, nullptr, 1024, EMBED, 1.0f);
  // 3c. V projection from kv_feat -> transposed Vt [4][512][4096]
  gemm_bt_kernel<3><<<dim3(MTOT / 128, 4), 256, 0, stream>>>(
      Akv, Wcat + 1024 * 1024, Vt, nullptr, nullptr, 0, EMBED, 1.0f);
  // 4. flash attention: Q-tile 128, 8 waves, d-slice PV, LDS-reorg epilogue
  flash_kernel<<<dim3(SEQ / QT, NBATCH, KVSPLIT), 512, 0, stream>>>(QKV, Vt, Opart, mlp);
  // 4b. combine partials -> bf16 ctx
  combine_kernel<<<MTOT, 128, 0, stream>>>(Opart, mlp, ctx);
  // 5. out1 = ctx @ Wo^T + bo + q_feat  (bf16)
  gemm_bt_kernel<1><<<dim3(MTOT / 128, EMBED / 128), 256, 0, stream>>>(
      ctx, Wo_t, out1, bo, q_feat, EMBED, HIDDEN, 0.f);
  // 6. out2 = out1 @ Wfc^T (fp32 -> d_out)
  gemm_bt_kernel<2><<<dim3(MTOT / 128, EMBED / 128), 256, 0, stream>>>(
      out1, Wfc_t, out, nullptr, nullptr, EMBED, EMBED, 0.f);
  // 7. layernorm in-place
  ln_kernel<<<MTOT, 256, 0, stream>>>(out, ln_g, ln_b);

  (void)in_sizes; (void)n_in; (void)out_size; (void)ws_size;
}

// Round 9
// 672.975 us; speedup vs baseline: 1.1817x; 1.1817x over previous
//
#include <hip/hip_runtime.h>
#include <hip/hip_bf16.h>
#include <cstdint>

// ---------- types ----------
typedef __bf16 bf16x8 __attribute__((ext_vector_type(8)));
typedef float f32x4 __attribute__((ext_vector_type(4)));
typedef unsigned short u16;
typedef unsigned short u16x8 __attribute__((ext_vector_type(8)));
typedef unsigned short u16x4 __attribute__((ext_vector_type(4)));

#define EMBED 1024
#define HIDDEN 512
#define SEQ 4096
#define NBATCH 4
#define MTOT (NBATCH * SEQ)  // 16384
#define KVSPLIT 2
#define QT 128               // q-rows per flash block (8 waves x 16 rows)

__device__ __forceinline__ u16 f32_to_bf16(float f) {
  union { float f; uint32_t u; } v; v.f = f;
  uint32_t r = v.u + 0x7fffu + ((v.u >> 16) & 1u);
  return (u16)(r >> 16);
}

// async global->LDS, 16B per lane; lds dst MUST be wave-uniform; HW adds lane*16B
__device__ __forceinline__ void load_lds16(const u16* g, u16* l) {
  __builtin_amdgcn_global_load_lds(
      (const __attribute__((address_space(1))) void*)g,
      (__attribute__((address_space(3))) void*)l, 16, 0, 0);
}

// ---------- elementwise f32 -> bf16 ----------
__global__ __launch_bounds__(256) void cvt_bf16_kernel(const float* __restrict__ src,
                                                       u16* __restrict__ dst) {
  int i = blockIdx.x * 256 + threadIdx.x;
  float4 v = ((const float4*)src)[i];
  u16x4 o;
  o[0] = f32_to_bf16(v.x); o[1] = f32_to_bf16(v.y);
  o[2] = f32_to_bf16(v.z); o[3] = f32_to_bf16(v.w);
  ((u16x4*)dst)[i] = o;
}

// ---------- weight transpose+convert: src[K][N] f32 -> dst[N][K] bf16 ----------
__global__ __launch_bounds__(256) void transpose_w_kernel(const float* __restrict__ src,
                                                          u16* __restrict__ dst,
                                                          int log2N, int K) {
  int idx = blockIdx.x * 256 + threadIdx.x;
  int N = 1 << log2N;
  int k = idx >> log2N;
  int n = idx & (N - 1);
  dst[(size_t)n * K + k] = f32_to_bf16(src[idx]);
}

// ---------- GEMM: C[M,N] = A[M,K] * Bt[N,K]^T  (bf16 in, fp32 acc) ----------
// m97 structure: width-16 global_load_lds staging into UNPADDED [128][32] tiles.
// LDS dst is WAVE-UNIFORM (&As[16*wave][0]); HW writes base + lane*16B, so lane L
// covers (row = 16*wave + L/4, lds col-block = L&3). Global source col-block is
// pre-swizzled by (row>>1)&3 (rule #21); ds_read applies the same XOR.
// MODE 0: bf16 out * scale
// MODE 1: bf16 out, + bias[col] + resid[row*ldc+col]
// MODE 2: fp32 out
// MODE 3: bf16 out TRANSPOSED per batch: Vt[(batch*512+col)*4096 + (row&4095)]
template <int MODE>
__global__ __launch_bounds__(256, 3) void gemm_bt_kernel(
    const u16* __restrict__ A, const u16* __restrict__ Bt, void* __restrict__ Cout,
    const float* __restrict__ bias, const float* __restrict__ resid,
    int ldc, int K, float scale) {
  __shared__ u16 As[128][32];
  __shared__ u16 Bs[128][32];
  const int tid = threadIdx.x;
  const int lane = tid & 63;
  const int wave = tid >> 6;
  const int quad = lane >> 4;
  const int l15 = lane & 15;
  const int m0 = blockIdx.x * 128;
  const int n0 = blockIdx.y * 128;
  const int wm = (wave & 1) * 64;
  const int wn = (wave >> 1) * 64;

  // staging: lane L of wave w covers row 16w + L/4 (chunk0) / +64 (chunk1),
  // source col-block swizzled by ((row within 16)>>1)&3 = (L>>3)&3.
  const int rw = wave * 16 + (lane >> 2);
  const int cb = ((lane & 3) ^ ((lane >> 3) & 3)) * 8;
  const u16* pa0 = &A[(size_t)(m0 + rw) * K + cb];
  const u16* pb0 = &Bt[(size_t)(n0 + rw) * K + cb];
  u16* lA = &As[wave * 16][0];   // wave-uniform LDS base
  u16* lB = &Bs[wave * 16][0];

  f32x4 acc[4][4];
#pragma unroll
  for (int i = 0; i < 4; ++i)
#pragma unroll
    for (int j = 0; j < 4; ++j) {
      acc[i][j][0] = 0.f; acc[i][j][1] = 0.f; acc[i][j][2] = 0.f; acc[i][j][3] = 0.f;
    }

  for (int k0 = 0; k0 < K; k0 += 32) {
    __syncthreads();
    load_lds16(pa0 + k0, lA);
    load_lds16(pa0 + k0 + (size_t)64 * K, lA + 64 * 32);   // rows 64..127
    load_lds16(pb0 + k0, lB);
    load_lds16(pb0 + k0 + (size_t)64 * K, lB + 64 * 32);
    __syncthreads();                                       // drains vmcnt(0): tiles ready
    bf16x8 af[4], bfr[4];
#pragma unroll
    for (int i = 0; i < 4; ++i)
      af[i] = *(const bf16x8*)&As[wm + i * 16 + l15][(quad ^ ((l15 >> 1) & 3)) * 8];
#pragma unroll
    for (int j = 0; j < 4; ++j)
      bfr[j] = *(const bf16x8*)&Bs[wn + j * 16 + l15][(quad ^ ((l15 >> 1) & 3)) * 8];
#pragma unroll
    for (int i = 0; i < 4; ++i)
#pragma unroll
      for (int j = 0; j < 4; ++j)
        acc[i][j] = __builtin_amdgcn_mfma_f32_16x16x32_bf16(af[i], bfr[j], acc[i][j], 0, 0, 0);
  }

  // epilogue: C/D layout col=lane&15, row=quad*4+reg  [guide m89/m91]
#pragma unroll
  for (int i = 0; i < 4; ++i) {
    const int row = m0 + wm + i * 16 + quad * 4;
#pragma unroll
    for (int j = 0; j < 4; ++j) {
      const int col = n0 + wn + j * 16 + l15;
#pragma unroll
      for (int r = 0; r < 4; ++r) {
        float v = acc[i][j][r];
        const int rr = row + r;
        if (MODE == 0) {
          ((u16*)Cout)[(size_t)rr * ldc + col] = f32_to_bf16(v * scale);
        } else if (MODE == 1) {
          const size_t off = (size_t)rr * ldc + col;
          v += bias[col] + resid[off];
          ((u16*)Cout)[off] = f32_to_bf16(v);
        } else if (MODE == 2) {
          ((float*)Cout)[(size_t)rr * ldc + col] = v;
        } else {
          // transposed V store
          ((u16*)Cout)[((size_t)((rr >> 12) * 512 + col) << 12) + (rr & 4095)] = f32_to_bf16(v);
        }
      }
    }
  }
}

// ---------- flash attention (2-way KV split, Q-tile 128, d-slice PV) ----------
// QKV: [16384, 1024] bf16 rows (Q|K), Q pre-scaled by log2(e)/sqrt(512).
// VtG: [4][512][4096] bf16 (V transposed per batch).
// grid (SEQ/QT=32, NBATCH, KVSPLIT); block 512 = 8 waves.
// Phase A (per wave, its own q-group g=wave): QK^T 16q x 32kv, exp2, publish P.
// Phase B (after barrier): wave w owns d-slice nt in [4w,4w+4) for ALL 8 groups —
// V frags read ONCE per iter (4 b128, reused across groups); P frags 8 b128.
// R8 lesson: an 8-WAVE BLOCK means 2 waves/SIMD minimum, so the unified reg
// file hard-caps 256 regs/wave no matter what launch_bounds says. The live set
// (O 128 + qf 64 + vf 16 + temps) exceeded it -> persistent scratch spill
// (592 MB WRITE). Fix: keep only HALF of Q resident (qf[8], K in [0,256));
// reload the other half (q2[8]) from global EVERY iteration — 8 KB/wave/iter,
// L2-served, issued BEFORE STAGE so its counted waitcnt doesn't drain staging.
// asm opaque-pointer per iter stops LICM from hoisting q2 back into registers.
// Peak live ~220 < 256 -> no spill.
// NO max-subtraction (scores bounded; exp2 domain); lane-local l, epilogue reduce.
// 2-phase dbuf pipeline: STAGE(next) at iter top; vmcnt(0)+barrier at iter end.
__global__ __launch_bounds__(512, 1) void flash_kernel(const u16* __restrict__ QKV,
                                                       const u16* __restrict__ VtG,
                                                       float* __restrict__ Opart,
                                                       float* __restrict__ ml) {
  __shared__ u16 Ks[2][32][520];   // K tile [kv][d], pad 512+8; epilogue scratch alias
  __shared__ u16 Vs[2][512][32];   // V^T tile [d][kv]; col-block XOR-swizzled by (row>>1)&3
  __shared__ u16 Ps[8][16][40];    // P tiles [group][q][kv] (80B rows: 16B-aligned, 2-way max)
  const int tid = threadIdx.x;
  const int lane = tid & 63;
  const int wave = tid >> 6;       // 0..7 = q-group (phase A) and d-slice owner (phase B)
  const int quad = lane >> 4;
  const int l15 = lane & 15;
  // --- XCD-aware remap: raw = bx + 32*by + 128*bz in [0,256); id%8 picks XCD.
  const int raw = blockIdx.x + 32 * blockIdx.y + 128 * blockIdx.z;
  const int xh = raw >> 3;
  const int g8 = raw & 7;
  const int yh = g8 >> 1;
  const int zh = g8 & 1;
  const int base = yh * SEQ;
  const int b512 = yh * 512;
  const int q0 = xh * QT;
  const int kvb = zh * (SEQ / KVSPLIT);

  // Q fragments: A-layout m=lane&15, k=quad*8+j [guide m120]. HALF resident
  // (K cols [0,256)); other half re-loaded per-iter from global (L2-resident).
  const u16* qp = QKV + (size_t)(base + q0 + wave * 16 + l15) * 1024 + quad * 8;
  bf16x8 qf[8];
#pragma unroll
  for (int ks = 0; ks < 8; ++ks) qf[ks] = *(const bf16x8*)(qp + ks * 32);

  // O[g][j]: q-group g, local d-tile j (global nt = wave*4+j). ALL accesses
  // statically indexed (rule #20).
  f32x4 O[8][4];
#pragma unroll
  for (int g = 0; g < 8; ++g)
#pragma unroll
    for (int j = 0; j < 4; ++j) { O[g][j][0] = 0.f; O[g][j][1] = 0.f; O[g][j][2] = 0.f; O[g][j][3] = 0.f; }
  float l_run[4] = {0.f, 0.f, 0.f, 0.f};  // lane-local partial row-sums (group=wave)

  // stage one 32-kv tile (K 32KB + V^T 32KB) into buffer b: 8 loads/wave
  auto STAGE = [&](int b, int kv0) {
    const u16* kp = QKV + (size_t)(base + kv0 + wave * 4) * 1024 + 512 + lane * 8;
    const u16* vp = VtG + (size_t)(b512 + wave * 64 + (lane >> 2)) * 4096 + kv0 +
                    (((lane & 3) ^ ((lane >> 3) & 3)) * 8);
#pragma unroll
    for (int p = 0; p < 4; ++p) {
      load_lds16(kp + (size_t)p * 1024, &Ks[b][wave * 4 + p][0]);
      load_lds16(vp + (size_t)(p * 16) * 4096, &Vs[b][wave * 64 + p * 16][0]);
    }
  };

  const int nIter = (SEQ / KVSPLIT) / 32;  // 64
  STAGE(0, kvb);
  asm volatile("s_waitcnt vmcnt(0)" ::: "memory");
  __builtin_amdgcn_s_barrier();
  int cur = 0;

  for (int t = 0; t < nIter; ++t) {
    // q2 loads FIRST (oldest vm ops), then STAGE: the compiler's counted wait
    // for q2 use leaves the 8 stage loads in flight. Opaque pointer defeats LICM.
    const u16* qp2 = qp + 8 * 32;
    asm volatile("" : "+v"(qp2));
    bf16x8 q2[8];
#pragma unroll
    for (int ks = 0; ks < 8; ++ks) q2[ks] = *(const bf16x8*)(qp2 + ks * 32);

    if (t + 1 < nIter) STAGE(cur ^ 1, kvb + (t + 1) * 32);

    // Phase A: S tile for own q-group (16 q x 32 kv); first 8 K-steps use
    // resident qf (covers q2 load latency), last 8 use q2.
    f32x4 s0, s1;
    s0[0] = 0.f; s0[1] = 0.f; s0[2] = 0.f; s0[3] = 0.f;
    s1[0] = 0.f; s1[1] = 0.f; s1[2] = 0.f; s1[3] = 0.f;
    __builtin_amdgcn_s_setprio(1);
#pragma unroll
    for (int ks = 0; ks < 8; ++ks) {
      bf16x8 b0 = *(const bf16x8*)&Ks[cur][l15][ks * 32 + quad * 8];
      bf16x8 b1 = *(const bf16x8*)&Ks[cur][16 + l15][ks * 32 + quad * 8];
      s0 = __builtin_amdgcn_mfma_f32_16x16x32_bf16(qf[ks], b0, s0, 0, 0, 0);
      s1 = __builtin_amdgcn_mfma_f32_16x16x32_bf16(qf[ks], b1, s1, 0, 0, 0);
    }
#pragma unroll
    for (int ks = 0; ks < 8; ++ks) {
      bf16x8 b0 = *(const bf16x8*)&Ks[cur][l15][(ks + 8) * 32 + quad * 8];
      bf16x8 b1 = *(const bf16x8*)&Ks[cur][16 + l15][(ks + 8) * 32 + quad * 8];
      s0 = __builtin_amdgcn_mfma_f32_16x16x32_bf16(q2[ks], b0, s0, 0, 0, 0);
      s1 = __builtin_amdgcn_mfma_f32_16x16x32_bf16(q2[ks], b1, s1, 0, 0, 0);
    }
    __builtin_amdgcn_s_setprio(0);

    // preload this wave's 4 V frags (valid all iter; overlaps softmax VALU)
    bf16x8 vf[4];
#pragma unroll
    for (int j = 0; j < 4; ++j)
      vf[j] = *(const bf16x8*)&Vs[cur][(wave * 4 + j) * 16 + l15][(quad ^ ((l15 >> 1) & 3)) * 8];

    // softmax numerator: p = exp2(s); lane-local row-sum
    float p0[4], p1[4];
#pragma unroll
    for (int r = 0; r < 4; ++r) {
      p0[r] = __builtin_amdgcn_exp2f(s0[r]);
      p1[r] = __builtin_amdgcn_exp2f(s1[r]);
      l_run[r] += p0[r] + p1[r];
    }

    // publish P (C-layout scatter): group=wave rows, cols l15 / 16+l15
#pragma unroll
    for (int r = 0; r < 4; ++r) {
      Ps[wave][quad * 4 + r][l15] = f32_to_bf16(p0[r]);
      Ps[wave][quad * 4 + r][16 + l15] = f32_to_bf16(p1[r]);
    }
    asm volatile("s_waitcnt lgkmcnt(0)" ::: "memory");
    __builtin_amdgcn_s_barrier();    // #1: all P visible

    // Phase B: d-slice PV — 8 P reads + 4 resident V frags -> 32 MFMA
    __builtin_amdgcn_s_setprio(1);
#pragma unroll
    for (int g = 0; g < 8; ++g) {
      bf16x8 pf = *(const bf16x8*)&Ps[g][l15][quad * 8];
#pragma unroll
      for (int j = 0; j < 4; ++j)
        O[g][j] = __builtin_amdgcn_mfma_f32_16x16x32_bf16(pf, vf[j], O[g][j], 0, 0, 0);
    }
    __builtin_amdgcn_s_setprio(0);

    // #2: stage drained (next tiles ready) + all Ps reads done (safe to rewrite)
    asm volatile("s_waitcnt vmcnt(0) lgkmcnt(0)" ::: "memory");
    __builtin_amdgcn_s_barrier();
    cur ^= 1;
  }

  // epilogue: reduce l within quad (16 lanes hold the kv-slices of rows quad*4+r)
#pragma unroll
  for (int m = 1; m <= 8; m <<= 1)
#pragma unroll
    for (int r = 0; r < 4; ++r) l_run[r] += __shfl_xor(l_run[r], m);

  // l for own q-group (m=0 placeholder kept for combine kernel)
  if (l15 == 0) {
    const int qrow = base + q0 + wave * 16 + quad * 4;
#pragma unroll
    for (int r = 0; r < 4; ++r) {
      ml[((size_t)zh * MTOT + qrow + r) * 2 + 0] = 0.0f;
      ml[((size_t)zh * MTOT + qrow + r) * 2 + 1] = l_run[r];
    }
  }

  // epilogue O write: per group, gather d-slices in LDS then write coalesced rows.
  // sO [16][516] f32; FULLY UNROLLED group loop (rule #20: keep O in VGPRs).
  float* sO = (float*)&Ks[0][0][0];  // 33,024 B scratch, Ks dead after loop
  const int erow = tid >> 5;         // 0..15
  const int ecol = (tid & 31) * 16;  // 0..496
#pragma unroll
  for (int g = 0; g < 8; ++g) {
    // deposit: wave's d-slice of group g; row = quad*4+r, col = wave*64+j*16+l15
#pragma unroll
    for (int j = 0; j < 4; ++j)
#pragma unroll
      for (int r = 0; r < 4; ++r)
        sO[(quad * 4 + r) * 516 + wave * 64 + j * 16 + l15] = O[g][j][r];
    __syncthreads();
    // write 16 rows x 2KB contiguous: thread covers 64B of its row
    float* dst = Opart + ((size_t)zh * MTOT + base + q0 + g * 16 + erow) * HIDDEN + ecol;
    const float* srcp = sO + erow * 516 + ecol;
#pragma unroll
    for (int q = 0; q < 4; ++q)
      ((float4*)dst)[q] = ((const float4*)srcp)[q];
    __syncthreads();  // before next group overwrites sO
  }
}

// ---------- combine KV-split partials -> bf16 ctx ----------
__global__ __launch_bounds__(128) void combine_kernel(const float* __restrict__ Op,
                                                      const float* __restrict__ ml,
                                                      u16* __restrict__ ctx) {
  const int row = blockIdx.x;
  const int tid = threadIdx.x;  // 128 threads x float4 = 512 cols
  const float m1 = ml[(size_t)row * 2], l1 = ml[(size_t)row * 2 + 1];
  const float m2 = ml[((size_t)MTOT + row) * 2], l2 = ml[((size_t)MTOT + row) * 2 + 1];
  const float M = fmaxf(m1, m2);
  const float w1 = __expf(m1 - M), w2 = __expf(m2 - M);
  const float den = 1.0f / (w1 * l1 + w2 * l2);
  float4 a = ((const float4*)(Op + (size_t)row * HIDDEN))[tid];
  float4 b = ((const float4*)(Op + ((size_t)MTOT + row) * HIDDEN))[tid];
  u16x4 o;
  o[0] = f32_to_bf16((a.x * w1 + b.x * w2) * den);
  o[1] = f32_to_bf16((a.y * w1 + b.y * w2) * den);
  o[2] = f32_to_bf16((a.z * w1 + b.z * w2) * den);
  o[3] = f32_to_bf16((a.w * w1 + b.w * w2) * den);
  ((u16x4*)(ctx + (size_t)row * HIDDEN))[tid] = o;
}

// ---------- layernorm (in-place on d_out fp32, 1024 cols/row) ----------
__global__ __launch_bounds__(256) void ln_kernel(float* __restrict__ io,
                                                 const float* __restrict__ g,
                                                 const float* __restrict__ b) {
  const int row = blockIdx.x;
  const int tid = threadIdx.x;
  float* x = io + (size_t)row * EMBED;
  float4 v = *(const float4*)(x + tid * 4);
  float s1 = v.x + v.y + v.z + v.w;
  float s2 = v.x * v.x + v.y * v.y + v.z * v.z + v.w * v.w;
#pragma unroll
  for (int m = 1; m <= 32; m <<= 1) {
    s1 += __shfl_xor(s1, m);
    s2 += __shfl_xor(s2, m);
  }
  __shared__ float rs1[4], rs2[4];
  const int wave = tid >> 6;
  if ((tid & 63) == 0) { rs1[wave] = s1; rs2[wave] = s2; }
  __syncthreads();
  s1 = rs1[0] + rs1[1] + rs1[2] + rs1[3];
  s2 = rs2[0] + rs2[1] + rs2[2] + rs2[3];
  const float mu = s1 * (1.f / EMBED);
  const float var = s2 * (1.f / EMBED) - mu * mu;
  const float rinv = rsqrtf(var + 1e-5f);
  float4 gg = *(const float4*)(g + tid * 4);
  float4 bb = *(const float4*)(b + tid * 4);
  float4 o;
  o.x = (v.x - mu) * rinv * gg.x + bb.x;
  o.y = (v.y - mu) * rinv * gg.y + bb.y;
  o.z = (v.z - mu) * rinv * gg.z + bb.z;
  o.w = (v.w - mu) * rinv * gg.w + bb.w;
  *(float4*)(x + tid * 4) = o;
}

// ---------- launch ----------
extern "C" void kernel_launch(void* const* d_in, const int* in_sizes, int n_in,
                              void* d_out, int out_size, void* d_ws, size_t ws_size,
                              hipStream_t stream) {
  const float* q_feat = (const float*)d_in[0];
  const float* kv_feat = (const float*)d_in[1];
  const float* Wq = (const float*)d_in[2];
  const float* Wk = (const float*)d_in[3];
  const float* Wv = (const float*)d_in[4];
  const float* Wo = (const float*)d_in[5];
  const float* bo = (const float*)d_in[6];
  const float* Wfc = (const float*)d_in[7];
  const float* ln_g = (const float*)d_in[8];
  const float* ln_b = (const float*)d_in[9];
  float* out = (float*)d_out;

  // ws carve (total 140,509,184 B)
  char* ws = (char*)d_ws;
  u16* Aq    = (u16*)(ws + 0);           // 33,554,432  (later aliased as Opart/out1)
  u16* Akv   = (u16*)(ws + 33554432);    // 33,554,432  (later aliased as Opart upper half)
  u16* Wcat  = (u16*)(ws + 67108864);    //  3,145,728  [1536,1024] bf16 (Wq^T|Wk^T|Wv^T); later ml
  u16* Wo_t  = (u16*)(ws + 70254592);    //  1,048,576  [1024,512]
  u16* Wfc_t = (u16*)(ws + 71303168);    //  2,097,152  [1024,1024]
  u16* QKV   = (u16*)(ws + 73400320);    // 33,554,432  [16384,1024] (Q|K)
  u16* Vt    = (u16*)(ws + 106954752);   // 16,777,216  [4][512][4096]
  u16* ctx   = (u16*)(ws + 123731968);   // 16,777,216  [16384,512]
  u16* out1  = Aq;                       // alias: Aq dead after Q-projection
  // flash partials alias dead regions: Aq+Akv (dead after projections) hold
  // Opart [2][16384][512] f32 = 67,108,864 B; first 256 KB of Wcat (dead after
  // projections) holds ml [2][16384][2] f32 = 262,144 B.
  float* Opart = (float*)(ws + 0);
  float* mlp   = (float*)(ws + 67108864);

  // Q pre-scale: log2(e)/sqrt(512) so scores arrive in log2 domain (p = exp2(s))
  const float qscale = 0.063762994f;

  // 1. activations -> bf16
  cvt_bf16_kernel<<<MTOT * EMBED / 1024, 256, 0, stream>>>(q_feat, Aq);
  cvt_bf16_kernel<<<MTOT * EMBED / 1024, 256, 0, stream>>>(kv_feat, Akv);
  // 2. weights -> transposed bf16
  transpose_w_kernel<<<(EMBED * HIDDEN) / 256, 256, 0, stream>>>(Wq, Wcat, 9, EMBED);
  transpose_w_kernel<<<(EMBED * HIDDEN) / 256, 256, 0, stream>>>(Wk, Wcat + 512 * 1024, 9, EMBED);
  transpose_w_kernel<<<(EMBED * HIDDEN) / 256, 256, 0, stream>>>(Wv, Wcat + 1024 * 1024, 9, EMBED);
  transpose_w_kernel<<<(HIDDEN * EMBED) / 256, 256, 0, stream>>>(Wo, Wo_t, 10, HIDDEN);
  transpose_w_kernel<<<(EMBED * EMBED) / 256, 256, 0, stream>>>(Wfc, Wfc_t, 10, EMBED);
  // 3a. Q projection from q_feat (pre-scaled): QKV cols [0,512)
  gemm_bt_kernel<0><<<dim3(MTOT / 128, 4), 256, 0, stream>>>(
      Aq, Wcat, QKV, nullptr, nullptr, 1024, EMBED, qscale);
  // 3b. K projection from kv_feat: QKV cols [512,1024)
  gemm_bt_kernel<0><<<dim3(MTOT / 128, 4), 256, 0, stream>>>(
      Akv, Wcat + 512 * 1024, QKV + 512, nullptr, nullptr, 1024, EMBED, 1.0f);
  // 3c. V projection from kv_feat -> transposed Vt [4][512][4096]
  gemm_bt_kernel<3><<<dim3(MTOT / 128, 4), 256, 0, stream>>>(
      Akv, Wcat + 1024 * 1024, Vt, nullptr, nullptr, 0, EMBED, 1.0f);
  // 4. flash attention: Q-tile 128, 8 waves, d-slice PV, half-resident Q
  flash_kernel<<<dim3(SEQ / QT, NBATCH, KVSPLIT), 512, 0, stream>>>(QKV, Vt, Opart, mlp);
  // 4b. combine partials -> bf16 ctx
  combine_kernel<<<MTOT, 128, 0, stream>>>(Opart, mlp, ctx);
  // 5. out1 = ctx @ Wo^T + bo + q_feat  (bf16)
  gemm_bt_kernel<1><<<dim3(MTOT / 128, EMBED / 128), 256, 0, stream>>>(
      ctx, Wo_t, out1, bo, q_feat, EMBED, HIDDEN, 0.f);
  // 6. out2 = out1 @ Wfc^T (fp32 -> d_out)
  gemm_bt_kernel<2><<<dim3(MTOT / 128, EMBED / 128), 256, 0, stream>>>(
      out1, Wfc_t, out, nullptr, nullptr, EMBED, EMBED, 0.f);
  // 7. layernorm in-place
  ln_kernel<<<MTOT, 256, 0, stream>>>(out, ln_g, ln_b);

  (void)in_sizes; (void)n_in; (void)out_size; (void)ws_size;
}

// Round 10
// 606.840 us; speedup vs baseline: 1.3105x; 1.1090x over previous
//
#include <hip/hip_runtime.h>
#include <hip/hip_bf16.h>
#include <cstdint>

// ---------- types ----------
typedef __bf16 bf16x8 __attribute__((ext_vector_type(8)));
typedef float f32x4 __attribute__((ext_vector_type(4)));
typedef unsigned short u16;
typedef unsigned short u16x8 __attribute__((ext_vector_type(8)));
typedef unsigned short u16x4 __attribute__((ext_vector_type(4)));

#define EMBED 1024
#define HIDDEN 512
#define SEQ 4096
#define NBATCH 4
#define MTOT (NBATCH * SEQ)  // 16384
#define KVSPLIT 2
#define QT 128               // q-rows per flash block (8 waves x 16 rows)

__device__ __forceinline__ u16 f32_to_bf16(float f) {
  union { float f; uint32_t u; } v; v.f = f;
  uint32_t r = v.u + 0x7fffu + ((v.u >> 16) & 1u);
  return (u16)(r >> 16);
}

// async global->LDS, 16B per lane; lds dst MUST be wave-uniform; HW adds lane*16B
__device__ __forceinline__ void load_lds16(const u16* g, u16* l) {
  __builtin_amdgcn_global_load_lds(
      (const __attribute__((address_space(1))) void*)g,
      (__attribute__((address_space(3))) void*)l, 16, 0, 0);
}

// ---------- elementwise f32 -> bf16 ----------
__global__ __launch_bounds__(256) void cvt_bf16_kernel(const float* __restrict__ src,
                                                       u16* __restrict__ dst) {
  int i = blockIdx.x * 256 + threadIdx.x;
  float4 v = ((const float4*)src)[i];
  u16x4 o;
  o[0] = f32_to_bf16(v.x); o[1] = f32_to_bf16(v.y);
  o[2] = f32_to_bf16(v.z); o[3] = f32_to_bf16(v.w);
  ((u16x4*)dst)[i] = o;
}

// ---------- weight transpose+convert: src[K][N] f32 -> dst[N][K] bf16 ----------
__global__ __launch_bounds__(256) void transpose_w_kernel(const float* __restrict__ src,
                                                          u16* __restrict__ dst,
                                                          int log2N, int K) {
  int idx = blockIdx.x * 256 + threadIdx.x;
  int N = 1 << log2N;
  int k = idx >> log2N;
  int n = idx & (N - 1);
  dst[(size_t)n * K + k] = f32_to_bf16(src[idx]);
}

// ---------- GEMM: C[M,N] = A[M,K] * Bt[N,K]^T  (bf16 in, fp32 acc) ----------
// m97 structure: width-16 global_load_lds staging into UNPADDED [128][32] tiles.
// LDS dst is WAVE-UNIFORM (&As[16*wave][0]); HW writes base + lane*16B, so lane L
// covers (row = 16*wave + L/4, lds col-block = L&3). Global source col-block is
// pre-swizzled by (row>>1)&3 (rule #21); ds_read applies the same XOR.
// MODE 0: bf16 out * scale
// MODE 1: bf16 out, + bias[col] + resid[row*ldc+col]
// MODE 2: fp32 out
// MODE 3: bf16 out TRANSPOSED per batch: Vt[(batch*512+col)*4096 + (row&4095)]
template <int MODE>
__global__ __launch_bounds__(256, 3) void gemm_bt_kernel(
    const u16* __restrict__ A, const u16* __restrict__ Bt, void* __restrict__ Cout,
    const float* __restrict__ bias, const float* __restrict__ resid,
    int ldc, int K, float scale) {
  __shared__ u16 As[128][32];
  __shared__ u16 Bs[128][32];
  const int tid = threadIdx.x;
  const int lane = tid & 63;
  const int wave = tid >> 6;
  const int quad = lane >> 4;
  const int l15 = lane & 15;
  const int m0 = blockIdx.x * 128;
  const int n0 = blockIdx.y * 128;
  const int wm = (wave & 1) * 64;
  const int wn = (wave >> 1) * 64;

  // staging: lane L of wave w covers row 16w + L/4 (chunk0) / +64 (chunk1),
  // source col-block swizzled by ((row within 16)>>1)&3 = (L>>3)&3.
  const int rw = wave * 16 + (lane >> 2);
  const int cb = ((lane & 3) ^ ((lane >> 3) & 3)) * 8;
  const u16* pa0 = &A[(size_t)(m0 + rw) * K + cb];
  const u16* pb0 = &Bt[(size_t)(n0 + rw) * K + cb];
  u16* lA = &As[wave * 16][0];   // wave-uniform LDS base
  u16* lB = &Bs[wave * 16][0];

  f32x4 acc[4][4];
#pragma unroll
  for (int i = 0; i < 4; ++i)
#pragma unroll
    for (int j = 0; j < 4; ++j) {
      acc[i][j][0] = 0.f; acc[i][j][1] = 0.f; acc[i][j][2] = 0.f; acc[i][j][3] = 0.f;
    }

  for (int k0 = 0; k0 < K; k0 += 32) {
    __syncthreads();
    load_lds16(pa0 + k0, lA);
    load_lds16(pa0 + k0 + (size_t)64 * K, lA + 64 * 32);   // rows 64..127
    load_lds16(pb0 + k0, lB);
    load_lds16(pb0 + k0 + (size_t)64 * K, lB + 64 * 32);
    __syncthreads();                                       // drains vmcnt(0): tiles ready
    bf16x8 af[4], bfr[4];
#pragma unroll
    for (int i = 0; i < 4; ++i)
      af[i] = *(const bf16x8*)&As[wm + i * 16 + l15][(quad ^ ((l15 >> 1) & 3)) * 8];
#pragma unroll
    for (int j = 0; j < 4; ++j)
      bfr[j] = *(const bf16x8*)&Bs[wn + j * 16 + l15][(quad ^ ((l15 >> 1) & 3)) * 8];
#pragma unroll
    for (int i = 0; i < 4; ++i)
#pragma unroll
      for (int j = 0; j < 4; ++j)
        acc[i][j] = __builtin_amdgcn_mfma_f32_16x16x32_bf16(af[i], bfr[j], acc[i][j], 0, 0, 0);
  }

  // epilogue: C/D layout col=lane&15, row=quad*4+reg  [guide m89/m91]
#pragma unroll
  for (int i = 0; i < 4; ++i) {
    const int row = m0 + wm + i * 16 + quad * 4;
#pragma unroll
    for (int j = 0; j < 4; ++j) {
      const int col = n0 + wn + j * 16 + l15;
#pragma unroll
      for (int r = 0; r < 4; ++r) {
        float v = acc[i][j][r];
        const int rr = row + r;
        if (MODE == 0) {
          ((u16*)Cout)[(size_t)rr * ldc + col] = f32_to_bf16(v * scale);
        } else if (MODE == 1) {
          const size_t off = (size_t)rr * ldc + col;
          v += bias[col] + resid[off];
          ((u16*)Cout)[off] = f32_to_bf16(v);
        } else if (MODE == 2) {
          ((float*)Cout)[(size_t)rr * ldc + col] = v;
        } else {
          // transposed V store
          ((u16*)Cout)[((size_t)((rr >> 12) * 512 + col) << 12) + (rr & 4095)] = f32_to_bf16(v);
        }
      }
    }
  }
}

// ---------- flash attention (2-way KV split, Q-tile 128, R3 structure) ----------
// QKV: [16384, 1024] bf16 rows (Q|K), Q pre-scaled by log2(e)/sqrt(512).
// VtG: [4][512][4096] bf16 (V transposed per batch).
// grid (SEQ/QT=32, NBATCH, KVSPLIT); block 512 = 8 waves; wave owns 16 q-rows,
// full D=512, NO intra-iter barrier (waves skew freely -> LDS port smoothing;
// R9 showed the barriered d-slice variant loses to this by 36%).
// R9->R10 change: SINGLE-buffered LDS (76.3 KB vs 142 KB) so TWO blocks fit per
// CU (launch_bounds (512,2)); inter-block TLP hides the staging drain that
// double-buffering was paying LDS for (1 block/CU had no other block to run).
// NO max-subtraction (scores bounded; exp2 domain); lane-local l, epilogue reduce.
__global__ __launch_bounds__(512, 2) void flash_kernel(const u16* __restrict__ QKV,
                                                       const u16* __restrict__ VtG,
                                                       float* __restrict__ Opart,
                                                       float* __restrict__ ml) {
  __shared__ u16 Ks[32][520];      // K tile [kv][d], pad 512+8 (pad BETWEEN rows ok for lds-dma)
  __shared__ u16 Vs[512][32];      // V^T tile [d][kv]; col-block XOR-swizzled by (row>>1)&3
  __shared__ u16 Ps[8][16][40];    // per-wave P round-trip [qrow][kv]
  const int tid = threadIdx.x;
  const int lane = tid & 63;
  const int wave = tid >> 6;
  const int quad = lane >> 4;
  const int l15 = lane & 15;
  // --- XCD-aware remap: raw = bx + 32*by + 128*bz in [0,256); id%8 picks XCD.
  const int raw = blockIdx.x + 32 * blockIdx.y + 128 * blockIdx.z;
  const int xh = raw >> 3;
  const int g8 = raw & 7;
  const int yh = g8 >> 1;
  const int zh = g8 & 1;
  const int base = yh * SEQ;
  const int b512 = yh * 512;
  const int q0 = xh * QT;
  const int kvb = zh * (SEQ / KVSPLIT);

  // Q fragments resident in registers: A-layout m=lane&15, k=quad*8+j  [guide m120]
  bf16x8 qf[16];
  {
    const u16* qp = QKV + (size_t)(base + q0 + wave * 16 + l15) * 1024 + quad * 8;
#pragma unroll
    for (int ks = 0; ks < 16; ++ks) qf[ks] = *(const bf16x8*)(qp + ks * 32);
  }

  f32x4 O[32];
#pragma unroll
  for (int i = 0; i < 32; ++i) { O[i][0] = 0.f; O[i][1] = 0.f; O[i][2] = 0.f; O[i][3] = 0.f; }
  float l_run[4] = {0.f, 0.f, 0.f, 0.f};  // lane-local partial row-sums

  // stage one 32-kv tile (K 32KB + V^T 32KB): 8 loads/wave
  auto STAGE = [&](int kv0) {
    const u16* kp = QKV + (size_t)(base + kv0 + wave * 4) * 1024 + 512 + lane * 8;
    const u16* vp = VtG + (size_t)(b512 + wave * 64 + (lane >> 2)) * 4096 + kv0 +
                    (((lane & 3) ^ ((lane >> 3) & 3)) * 8);
#pragma unroll
    for (int p = 0; p < 4; ++p) {
      load_lds16(kp + (size_t)p * 1024, &Ks[wave * 4 + p][0]);
      load_lds16(vp + (size_t)(p * 16) * 4096, &Vs[wave * 64 + p * 16][0]);
    }
  };

  const int nIter = (SEQ / KVSPLIT) / 32;  // 64
  for (int t = 0; t < nIter; ++t) {
    __syncthreads();                      // prev tile fully consumed by all waves
    STAGE(kvb + t * 32);
    asm volatile("s_waitcnt vmcnt(0)" ::: "memory");
    __builtin_amdgcn_s_barrier();         // tile ready for all waves

    // S tile: 16 q-rows x 32 kv-cols (two 16x16 MFMA col-tiles)
    f32x4 s0, s1;
    s0[0] = 0.f; s0[1] = 0.f; s0[2] = 0.f; s0[3] = 0.f;
    s1[0] = 0.f; s1[1] = 0.f; s1[2] = 0.f; s1[3] = 0.f;
    __builtin_amdgcn_s_setprio(1);
#pragma unroll
    for (int ks = 0; ks < 16; ++ks) {
      bf16x8 b0 = *(const bf16x8*)&Ks[l15][ks * 32 + quad * 8];
      bf16x8 b1 = *(const bf16x8*)&Ks[16 + l15][ks * 32 + quad * 8];
      s0 = __builtin_amdgcn_mfma_f32_16x16x32_bf16(qf[ks], b0, s0, 0, 0, 0);
      s1 = __builtin_amdgcn_mfma_f32_16x16x32_bf16(qf[ks], b1, s1, 0, 0, 0);
    }
    __builtin_amdgcn_s_setprio(0);

    // softmax numerator: p = exp2(s); lane-local row-sum (no cross-lane work)
    float p0[4], p1[4];
#pragma unroll
    for (int r = 0; r < 4; ++r) {
      p0[r] = __builtin_amdgcn_exp2f(s0[r]);
      p1[r] = __builtin_amdgcn_exp2f(s1[r]);
      l_run[r] += p0[r] + p1[r];
    }

    // P: C-layout -> LDS -> A-layout (wave-private: waitcnt, no barrier)
#pragma unroll
    for (int r = 0; r < 4; ++r) {
      Ps[wave][quad * 4 + r][l15] = f32_to_bf16(p0[r]);
      Ps[wave][quad * 4 + r][16 + l15] = f32_to_bf16(p1[r]);
    }
    asm volatile("s_waitcnt lgkmcnt(0)" ::: "memory");
    bf16x8 pf = *(const bf16x8*)&Ps[wave][l15][quad * 8];
    __builtin_amdgcn_s_setprio(1);
#pragma unroll
    for (int nt = 0; nt < 32; ++nt) {
      // swizzled V read: col-block = quad ^ ((row>>1)&3), row = nt*16+l15
      bf16x8 vf = *(const bf16x8*)&Vs[nt * 16 + l15][(quad ^ ((l15 >> 1) & 3)) * 8];
      O[nt] = __builtin_amdgcn_mfma_f32_16x16x32_bf16(pf, vf, O[nt], 0, 0, 0);
    }
    __builtin_amdgcn_s_setprio(0);
  }

  // epilogue: reduce l within quad (16 lanes hold the kv-slices of rows quad*4+r)
#pragma unroll
  for (int m = 1; m <= 8; m <<= 1)
#pragma unroll
    for (int r = 0; r < 4; ++r) l_run[r] += __shfl_xor(l_run[r], m);

  // unnormalized partial O (f32) + per-row (m=0, l)
  const int qrow = base + q0 + wave * 16 + quad * 4;
  float* op = Opart + ((size_t)zh * MTOT + qrow) * HIDDEN;
#pragma unroll
  for (int nt = 0; nt < 32; ++nt)
#pragma unroll
    for (int r = 0; r < 4; ++r)
      op[(size_t)r * HIDDEN + nt * 16 + l15] = O[nt][r];
  if (l15 == 0) {
#pragma unroll
    for (int r = 0; r < 4; ++r) {
      ml[((size_t)zh * MTOT + qrow + r) * 2 + 0] = 0.0f;
      ml[((size_t)zh * MTOT + qrow + r) * 2 + 1] = l_run[r];
    }
  }
}

// ---------- combine KV-split partials -> bf16 ctx ----------
__global__ __launch_bounds__(128) void combine_kernel(const float* __restrict__ Op,
                                                      const float* __restrict__ ml,
                                                      u16* __restrict__ ctx) {
  const int row = blockIdx.x;
  const int tid = threadIdx.x;  // 128 threads x float4 = 512 cols
  const float m1 = ml[(size_t)row * 2], l1 = ml[(size_t)row * 2 + 1];
  const float m2 = ml[((size_t)MTOT + row) * 2], l2 = ml[((size_t)MTOT + row) * 2 + 1];
  const float M = fmaxf(m1, m2);
  const float w1 = __expf(m1 - M), w2 = __expf(m2 - M);
  const float den = 1.0f / (w1 * l1 + w2 * l2);
  float4 a = ((const float4*)(Op + (size_t)row * HIDDEN))[tid];
  float4 b = ((const float4*)(Op + ((size_t)MTOT + row) * HIDDEN))[tid];
  u16x4 o;
  o[0] = f32_to_bf16((a.x * w1 + b.x * w2) * den);
  o[1] = f32_to_bf16((a.y * w1 + b.y * w2) * den);
  o[2] = f32_to_bf16((a.z * w1 + b.z * w2) * den);
  o[3] = f32_to_bf16((a.w * w1 + b.w * w2) * den);
  ((u16x4*)(ctx + (size_t)row * HIDDEN))[tid] = o;
}

// ---------- layernorm (in-place on d_out fp32, 1024 cols/row) ----------
__global__ __launch_bounds__(256) void ln_kernel(float* __restrict__ io,
                                                 const float* __restrict__ g,
                                                 const float* __restrict__ b) {
  const int row = blockIdx.x;
  const int tid = threadIdx.x;
  float* x = io + (size_t)row * EMBED;
  float4 v = *(const float4*)(x + tid * 4);
  float s1 = v.x + v.y + v.z + v.w;
  float s2 = v.x * v.x + v.y * v.y + v.z * v.z + v.w * v.w;
#pragma unroll
  for (int m = 1; m <= 32; m <<= 1) {
    s1 += __shfl_xor(s1, m);
    s2 += __shfl_xor(s2, m);
  }
  __shared__ float rs1[4], rs2[4];
  const int wave = tid >> 6;
  if ((tid & 63) == 0) { rs1[wave] = s1; rs2[wave] = s2; }
  __syncthreads();
  s1 = rs1[0] + rs1[1] + rs1[2] + rs1[3];
  s2 = rs2[0] + rs2[1] + rs2[2] + rs2[3];
  const float mu = s1 * (1.f / EMBED);
  const float var = s2 * (1.f / EMBED) - mu * mu;
  const float rinv = rsqrtf(var + 1e-5f);
  float4 gg = *(const float4*)(g + tid * 4);
  float4 bb = *(const float4*)(b + tid * 4);
  float4 o;
  o.x = (v.x - mu) * rinv * gg.x + bb.x;
  o.y = (v.y - mu) * rinv * gg.y + bb.y;
  o.z = (v.z - mu) * rinv * gg.z + bb.z;
  o.w = (v.w - mu) * rinv * gg.w + bb.w;
  *(float4*)(x + tid * 4) = o;
}

// ---------- launch ----------
extern "C" void kernel_launch(void* const* d_in, const int* in_sizes, int n_in,
                              void* d_out, int out_size, void* d_ws, size_t ws_size,
                              hipStream_t stream) {
  const float* q_feat = (const float*)d_in[0];
  const float* kv_feat = (const float*)d_in[1];
  const float* Wq = (const float*)d_in[2];
  const float* Wk = (const float*)d_in[3];
  const float* Wv = (const float*)d_in[4];
  const float* Wo = (const float*)d_in[5];
  const float* bo = (const float*)d_in[6];
  const float* Wfc = (const float*)d_in[7];
  const float* ln_g = (const float*)d_in[8];
  const float* ln_b = (const float*)d_in[9];
  float* out = (float*)d_out;

  // ws carve (total 140,509,184 B)
  char* ws = (char*)d_ws;
  u16* Aq    = (u16*)(ws + 0);           // 33,554,432  (later aliased as Opart/out1)
  u16* Akv   = (u16*)(ws + 33554432);    // 33,554,432  (later aliased as Opart upper half)
  u16* Wcat  = (u16*)(ws + 67108864);    //  3,145,728  [1536,1024] bf16 (Wq^T|Wk^T|Wv^T); later ml
  u16* Wo_t  = (u16*)(ws + 70254592);    //  1,048,576  [1024,512]
  u16* Wfc_t = (u16*)(ws + 71303168);    //  2,097,152  [1024,1024]
  u16* QKV   = (u16*)(ws + 73400320);    // 33,554,432  [16384,1024] (Q|K)
  u16* Vt    = (u16*)(ws + 106954752);   // 16,777,216  [4][512][4096]
  u16* ctx   = (u16*)(ws + 123731968);   // 16,777,216  [16384,512]
  u16* out1  = Aq;                       // alias: Aq dead after Q-projection
  // flash partials alias dead regions: Aq+Akv (dead after projections) hold
  // Opart [2][16384][512] f32 = 67,108,864 B; first 256 KB of Wcat (dead after
  // projections) holds ml [2][16384][2] f32 = 262,144 B.
  float* Opart = (float*)(ws + 0);
  float* mlp   = (float*)(ws + 67108864);

  // Q pre-scale: log2(e)/sqrt(512) so scores arrive in log2 domain (p = exp2(s))
  const float qscale = 0.063762994f;

  // 1. activations -> bf16
  cvt_bf16_kernel<<<MTOT * EMBED / 1024, 256, 0, stream>>>(q_feat, Aq);
  cvt_bf16_kernel<<<MTOT * EMBED / 1024, 256, 0, stream>>>(kv_feat, Akv);
  // 2. weights -> transposed bf16
  transpose_w_kernel<<<(EMBED * HIDDEN) / 256, 256, 0, stream>>>(Wq, Wcat, 9, EMBED);
  transpose_w_kernel<<<(EMBED * HIDDEN) / 256, 256, 0, stream>>>(Wk, Wcat + 512 * 1024, 9, EMBED);
  transpose_w_kernel<<<(EMBED * HIDDEN) / 256, 256, 0, stream>>>(Wv, Wcat + 1024 * 1024, 9, EMBED);
  transpose_w_kernel<<<(HIDDEN * EMBED) / 256, 256, 0, stream>>>(Wo, Wo_t, 10, HIDDEN);
  transpose_w_kernel<<<(EMBED * EMBED) / 256, 256, 0, stream>>>(Wfc, Wfc_t, 10, EMBED);
  // 3a. Q projection from q_feat (pre-scaled): QKV cols [0,512)
  gemm_bt_kernel<0><<<dim3(MTOT / 128, 4), 256, 0, stream>>>(
      Aq, Wcat, QKV, nullptr, nullptr, 1024, EMBED, qscale);
  // 3b. K projection from kv_feat: QKV cols [512,1024)
  gemm_bt_kernel<0><<<dim3(MTOT / 128, 4), 256, 0, stream>>>(
      Akv, Wcat + 512 * 1024, QKV + 512, nullptr, nullptr, 1024, EMBED, 1.0f);
  // 3c. V projection from kv_feat -> transposed Vt [4][512][4096]
  gemm_bt_kernel<3><<<dim3(MTOT / 128, 4), 256, 0, stream>>>(
      Akv, Wcat + 1024 * 1024, Vt, nullptr, nullptr, 0, EMBED, 1.0f);
  // 4. flash attention: R3 structure, single-buffer LDS, 2 blocks/CU
  flash_kernel<<<dim3(SEQ / QT, NBATCH, KVSPLIT), 512, 0, stream>>>(QKV, Vt, Opart, mlp);
  // 4b. combine partials -> bf16 ctx
  combine_kernel<<<MTOT, 128, 0, stream>>>(Opart, mlp, ctx);
  // 5. out1 = ctx @ Wo^T + bo + q_feat  (bf16)
  gemm_bt_kernel<1><<<dim3(MTOT / 128, EMBED / 128), 256, 0, stream>>>(
      ctx, Wo_t, out1, bo, q_feat, EMBED, HIDDEN, 0.f);
  // 6. out2 = out1 @ Wfc^T (fp32 -> d_out)
  gemm_bt_kernel<2><<<dim3(MTOT / 128, EMBED / 128), 256, 0, stream>>>(
      out1, Wfc_t, out, nullptr, nullptr, EMBED, EMBED, 0.f);
  // 7. layernorm in-place
  ln_kernel<<<MTOT, 256, 0, stream>>>(out, ln_g, ln_b);

  (void)in_sizes; (void)n_in; (void)out_size; (void)ws_size;
}